// Round 1
// baseline (2030.715 us; speedup 1.0000x reference)
//
#include <hip/hip_runtime.h>
#include <stdint.h>

#define NB 128
#define NC 512
#define NH 10
#define NW 20
#define NP 200      // NH*NW
#define ND3 1323
#define ND3P 1328   // padded channel count (16B-aligned rows)

typedef unsigned short u16;
typedef unsigned int u32;

// ---- workspace layout (bytes) ----
#define OFF_F      0ULL
#define SZ_F       (3ULL*NB*NC*NP*2)          // 78,643,200  bf16 f1/f2/f3
#define OFF_CORR   (OFF_F + SZ_F)
#define SZ_CORR    (1ULL*NB*NP*ND3P*2)        // 67,993,600  bf16 corr [b][p][d]
#define OFF_WCT    (OFF_CORR + SZ_CORR)
#define SZ_WCT     (9ULL*3*ND3P*4)            // transposed Wcorr [ky*3+kx][o][d]
#define OFF_WCATT  (OFF_WCT + SZ_WCT)
#define SZ_WCATT   (9ULL*3*1536*4)            // transposed Wcat  [ky*3+kx][o][i]
#define OFF_CFLAT  (OFF_WCATT + SZ_WCATT)
#define SZ_CFLAT   (1ULL*NB*600*4)
#define OFF_VFLAT  (OFF_CFLAT + SZ_CFLAT)
#define SZ_VFLAT   (1ULL*NB*600*4)

__device__ __forceinline__ float bf2f(u16 a) {
    return __uint_as_float(((u32)a) << 16);
}
__device__ __forceinline__ u16 f2bf(float x) {
    u32 u = __float_as_uint(x);
    return (u16)((u + 0x7fffu + ((u >> 16) & 1u)) >> 16);
}

// ---- transpose conv weights so inner d/i loops are contiguous ----
__global__ __launch_bounds__(256) void k_prep(const float* __restrict__ Wcorr,
                                              const float* __restrict__ Wcat,
                                              float* __restrict__ wct,
                                              float* __restrict__ wcatt) {
    int idx = blockIdx.x * 256 + threadIdx.x;
    const int n1 = 9 * 3 * ND3P;       // 35856
    const int n2 = 9 * 3 * 1536;       // 41472
    if (idx < n1) {
        int d = idx % ND3P;
        int r = idx / ND3P;
        int o = r % 3, k9 = r / 3;
        int ky = k9 / 3, kx = k9 % 3;
        float v = 0.0f;
        if (d < ND3) v = Wcorr[((o * ND3 + d) * 3 + ky) * 3 + kx];
        wct[idx] = v;
    } else if (idx < n1 + n2) {
        int j = idx - n1;
        int i = j % 1536;
        int r = j / 1536;
        int o = r % 3, k9 = r / 3;
        int ky = k9 / 3, kx = k9 % 3;
        wcatt[j] = Wcat[((o * 1536 + i) * 3 + ky) * 3 + kx];
    }
}

// ---- 1x1 conv: f_t = W_t * feat_t + b_t, fp32 compute, bf16 store ----
// grid (8 otiles, 3*128, 4 ptiles), block 256, tile 64x64, micro 4x4
__global__ __launch_bounds__(256) void k_conv1x1(
    const float* __restrict__ feat1, const float* __restrict__ feat2,
    const float* __restrict__ feat3,
    const float* __restrict__ Wa, const float* __restrict__ ba,
    const float* __restrict__ Wb, const float* __restrict__ bb,
    const float* __restrict__ Wc, const float* __restrict__ bc,
    u16* __restrict__ fout) {
    const int tid = threadIdx.x;
    const int t = blockIdx.y >> 7;
    const int b = blockIdx.y & 127;
    const int otile = blockIdx.x * 64;
    const int ptile = blockIdx.z * 64;
    const float* feat = (t == 0) ? feat1 : (t == 1) ? feat2 : feat3;
    const float* Wm   = (t == 0) ? Wa    : (t == 1) ? Wb    : Wc;
    const float* bias = (t == 0) ? ba    : (t == 1) ? bb    : bc;

    __shared__ float Ws[16][68];   // [k][o'], pad keeps 16B row alignment
    __shared__ float Fs[16][64];   // [k][p']

    const int tx = tid & 15, ty = tid >> 4;
    const int wo = tid >> 2;            // 0..63
    const int wc = (tid & 3) * 4;       // 0,4,8,12
    const int fx = (tid & 15) * 4;
    const int fc = tid >> 4;            // 0..15
    const int pf = ptile + fx;

    float acc[4][4] = {};

    for (int k0 = 0; k0 < NC; k0 += 16) {
        float4 wv = *(const float4*)&Wm[(size_t)(otile + wo) * NC + k0 + wc];
        float4 fv = make_float4(0.f, 0.f, 0.f, 0.f);
        if (pf < NP)
            fv = *(const float4*)&feat[((size_t)b * NC + (k0 + fc)) * NP + pf];
        __syncthreads();
        Ws[wc + 0][wo] = wv.x; Ws[wc + 1][wo] = wv.y;
        Ws[wc + 2][wo] = wv.z; Ws[wc + 3][wo] = wv.w;
        *(float4*)&Fs[fc][fx] = fv;
        __syncthreads();
#pragma unroll
        for (int k = 0; k < 16; ++k) {
            float4 a4 = *(const float4*)&Ws[k][ty * 4];
            float4 v4 = *(const float4*)&Fs[k][tx * 4];
            acc[0][0] = fmaf(a4.x, v4.x, acc[0][0]);
            acc[0][1] = fmaf(a4.x, v4.y, acc[0][1]);
            acc[0][2] = fmaf(a4.x, v4.z, acc[0][2]);
            acc[0][3] = fmaf(a4.x, v4.w, acc[0][3]);
            acc[1][0] = fmaf(a4.y, v4.x, acc[1][0]);
            acc[1][1] = fmaf(a4.y, v4.y, acc[1][1]);
            acc[1][2] = fmaf(a4.y, v4.z, acc[1][2]);
            acc[1][3] = fmaf(a4.y, v4.w, acc[1][3]);
            acc[2][0] = fmaf(a4.z, v4.x, acc[2][0]);
            acc[2][1] = fmaf(a4.z, v4.y, acc[2][1]);
            acc[2][2] = fmaf(a4.z, v4.z, acc[2][2]);
            acc[2][3] = fmaf(a4.z, v4.w, acc[2][3]);
            acc[3][0] = fmaf(a4.w, v4.x, acc[3][0]);
            acc[3][1] = fmaf(a4.w, v4.y, acc[3][1]);
            acc[3][2] = fmaf(a4.w, v4.z, acc[3][2]);
            acc[3][3] = fmaf(a4.w, v4.w, acc[3][3]);
        }
    }

    const int p = ptile + tx * 4;
    if (p < NP) {
#pragma unroll
        for (int i = 0; i < 4; ++i) {
            int o = otile + ty * 4 + i;
            float bi = bias[o];
            ushort4 st;
            st.x = f2bf(acc[i][0] + bi);
            st.y = f2bf(acc[i][1] + bi);
            st.z = f2bf(acc[i][2] + bi);
            st.w = f2bf(acc[i][3] + bi);
            *(ushort4*)&fout[(((size_t)t * NB + b) * NC + o) * NP + p] = st;
        }
    }
}

// ---- Gram + /512 + leaky_relu + scatter to corr[b][p1][pair*441+ch] ----
// grid (16 = 4x4 p-tiles, 3*128), block 256
__global__ __launch_bounds__(256) void k_gram(const u16* __restrict__ fbuf,
                                              u16* __restrict__ corr) {
    const int tid = threadIdx.x;
    const int pair = blockIdx.y >> 7;
    const int b = blockIdx.y & 127;
    const int p1t = (blockIdx.x >> 2) * 64;
    const int p2t = (blockIdx.x & 3) * 64;
    const int tA = (pair == 2) ? 1 : 0;
    const int tB = (pair == 0) ? 1 : 2;

    __shared__ float As[16][64];
    __shared__ float Bs[16][64];

    const int tx = tid & 15, ty = tid >> 4;
    const int lx = (tid & 15) * 4;
    const int lc = tid >> 4;           // 0..15
    const int pA = p1t + lx, pB = p2t + lx;

    float acc[4][4] = {};

    for (int k0 = 0; k0 < NC; k0 += 16) {
        ushort4 ua = make_ushort4(0, 0, 0, 0), ub = make_ushort4(0, 0, 0, 0);
        if (pA < NP)
            ua = *(const ushort4*)&fbuf[(((size_t)tA * NB + b) * NC + k0 + lc) * NP + pA];
        if (pB < NP)
            ub = *(const ushort4*)&fbuf[(((size_t)tB * NB + b) * NC + k0 + lc) * NP + pB];
        __syncthreads();
        *(float4*)&As[lc][lx] = make_float4(bf2f(ua.x), bf2f(ua.y), bf2f(ua.z), bf2f(ua.w));
        *(float4*)&Bs[lc][lx] = make_float4(bf2f(ub.x), bf2f(ub.y), bf2f(ub.z), bf2f(ub.w));
        __syncthreads();
#pragma unroll
        for (int k = 0; k < 16; ++k) {
            float4 a4 = *(const float4*)&As[k][ty * 4];
            float4 v4 = *(const float4*)&Bs[k][tx * 4];
            acc[0][0] = fmaf(a4.x, v4.x, acc[0][0]);
            acc[0][1] = fmaf(a4.x, v4.y, acc[0][1]);
            acc[0][2] = fmaf(a4.x, v4.z, acc[0][2]);
            acc[0][3] = fmaf(a4.x, v4.w, acc[0][3]);
            acc[1][0] = fmaf(a4.y, v4.x, acc[1][0]);
            acc[1][1] = fmaf(a4.y, v4.y, acc[1][1]);
            acc[1][2] = fmaf(a4.y, v4.z, acc[1][2]);
            acc[1][3] = fmaf(a4.y, v4.w, acc[1][3]);
            acc[2][0] = fmaf(a4.z, v4.x, acc[2][0]);
            acc[2][1] = fmaf(a4.z, v4.y, acc[2][1]);
            acc[2][2] = fmaf(a4.z, v4.z, acc[2][2]);
            acc[2][3] = fmaf(a4.z, v4.w, acc[2][3]);
            acc[3][0] = fmaf(a4.w, v4.x, acc[3][0]);
            acc[3][1] = fmaf(a4.w, v4.y, acc[3][1]);
            acc[3][2] = fmaf(a4.w, v4.z, acc[3][2]);
            acc[3][3] = fmaf(a4.w, v4.w, acc[3][3]);
        }
    }

#pragma unroll
    for (int i = 0; i < 4; ++i) {
        int p1 = p1t + ty * 4 + i;
        if (p1 >= NP) continue;
        int y1 = p1 / 20, x1 = p1 % 20;
#pragma unroll
        for (int j = 0; j < 4; ++j) {
            int p2 = p2t + tx * 4 + j;
            if (p2 >= NP) continue;
            int y2 = p2 / 20, x2 = p2 % 20;
            int oy = y2 - y1, ox = x2 - x1;
            if (((oy | ox) & 1) == 0) {
                int ch = ((oy + 20) >> 1) * 21 + ((ox + 20) >> 1);
                float v = acc[i][j] * (1.0f / 512.0f);
                v = (v > 0.0f) ? v : 0.1f * v;
                corr[((size_t)b * NP + p1) * ND3P + pair * 441 + ch] = f2bf(v);
            }
        }
    }
}

// ---- 3x3 conv over corr (1323->3) + bias + relu -> cflat[b][600] ----
// grid (10 rows, 128 b), block 256 (240 active: x(20) * o(3) * dchunk(4))
__global__ __launch_bounds__(256) void k_corrconv(const u16* __restrict__ corr,
                                                  const float* __restrict__ wct,
                                                  const float* __restrict__ bcorr,
                                                  float* __restrict__ cflat) {
    const int tid = threadIdx.x;
    const int y0 = blockIdx.x;
    const int b = blockIdx.y;
    float acc = 0.0f;
    if (tid < 240) {
        const int x = tid % 20;
        const int o = (tid / 20) % 3;
        const int dc = tid / 60;            // 0..3, chunks of 332
        for (int ky = 0; ky < 3; ++ky) {
            int yy = y0 + ky - 1;
            if (yy < 0 || yy >= NH) continue;
            for (int kx = 0; kx < 3; ++kx) {
                int xx = x + kx - 1;
                if (xx < 0 || xx >= NW) continue;
                int p = yy * 20 + xx;
                const ushort4* cp =
                    (const ushort4*)(corr + ((size_t)b * NP + p) * ND3P + dc * 332);
                const float4* wp =
                    (const float4*)(wct + ((size_t)(ky * 3 + kx) * 3 + o) * ND3P + dc * 332);
#pragma unroll 4
                for (int it = 0; it < 83; ++it) {
                    ushort4 cu = cp[it];
                    float4 wv = wp[it];
                    acc = fmaf(bf2f(cu.x), wv.x, acc);
                    acc = fmaf(bf2f(cu.y), wv.y, acc);
                    acc = fmaf(bf2f(cu.z), wv.z, acc);
                    acc = fmaf(bf2f(cu.w), wv.w, acc);
                }
            }
        }
    }
    __shared__ float red[256];
    red[tid] = acc;
    __syncthreads();
    if (tid < 60) {
        float s = red[tid] + red[tid + 60] + red[tid + 120] + red[tid + 180];
        int x = tid % 20, o = tid / 20;
        s += bcorr[o];
        s = fmaxf(s, 0.0f);
        cflat[(size_t)b * 600 + o * 200 + y0 * 20 + x] = s;
    }
}

// ---- 3x3 conv over concat(f1,f2,f3) (1536->3) + bias (no relu) -> vflat ----
__global__ __launch_bounds__(256) void k_catconv(const u16* __restrict__ fbuf,
                                                 const float* __restrict__ wcatt,
                                                 const float* __restrict__ bcat,
                                                 float* __restrict__ vflat) {
    const int tid = threadIdx.x;
    const int y0 = blockIdx.x;
    const int b = blockIdx.y;
    float acc = 0.0f;
    if (tid < 240) {
        const int x = tid % 20;
        const int o = (tid / 20) % 3;
        const int ic = tid / 60;          // chunks of 384 over i in [0,1536)
        const int base_i = ic * 384;
        for (int ky = 0; ky < 3; ++ky) {
            int yy = y0 + ky - 1;
            if (yy < 0 || yy >= NH) continue;
            for (int kx = 0; kx < 3; ++kx) {
                int xx = x + kx - 1;
                if (xx < 0 || xx >= NW) continue;
                int p = yy * 20 + xx;
                const float* wp = wcatt + ((size_t)(ky * 3 + kx) * 3 + o) * 1536 + base_i;
                int i = base_i, rem = 384, wi = 0;
                while (rem > 0) {
                    int t = i >> 9, c = i & 511;
                    int n = (rem < (512 - c)) ? rem : (512 - c);
                    const u16* fp = fbuf + (((size_t)t * NB + b) * NC + c) * NP + p;
#pragma unroll 4
                    for (int u = 0; u < n; ++u)
                        acc = fmaf(bf2f(fp[(size_t)u * NP]), wp[wi + u], acc);
                    i += n; wi += n; rem -= n;
                }
            }
        }
    }
    __shared__ float red[256];
    red[tid] = acc;
    __syncthreads();
    if (tid < 60) {
        float s = red[tid] + red[tid + 60] + red[tid + 120] + red[tid + 180];
        int x = tid % 20, o = tid / 20;
        s += bcat[o];
        vflat[(size_t)b * 600 + o * 200 + y0 * 20 + x] = s;
    }
}

// ---- fused MLPs + final linear. grid 128 (one block per batch row) ----
__global__ __launch_bounds__(256) void k_mlp(
    const float* __restrict__ cflat, const float* __restrict__ vflat,
    const float* __restrict__ cf_w1, const float* __restrict__ cf_b1,
    const float* __restrict__ cf_w2, const float* __restrict__ cf_b2,
    const float* __restrict__ ccf_w1, const float* __restrict__ ccf_b1,
    const float* __restrict__ ccf_w2, const float* __restrict__ ccf_b2,
    const float* __restrict__ Wout, const float* __restrict__ bout,
    float* __restrict__ out) {
    const int tid = threadIdx.x;
    const int b = blockIdx.x;
    __shared__ float cv[600], vv[600], h1[256], h2a[128], h2b[128];
    for (int k = tid; k < 600; k += 256) {
        cv[k] = cflat[(size_t)b * 600 + k];
        vv[k] = vflat[(size_t)b * 600 + k];
    }
    __syncthreads();
    // corr path layer 1 (600->256)
    {
        float s = cf_b1[tid];
        const float* wr = cf_w1 + (size_t)tid * 600;
        for (int k = 0; k < 600; k += 4) {
            float4 wv = *(const float4*)&wr[k];
            s = fmaf(cv[k], wv.x, s); s = fmaf(cv[k + 1], wv.y, s);
            s = fmaf(cv[k + 2], wv.z, s); s = fmaf(cv[k + 3], wv.w, s);
        }
        h1[tid] = fmaxf(s, 0.0f);
    }
    __syncthreads();
    if (tid < 128) {
        float s = cf_b2[tid];
        const float* wr = cf_w2 + (size_t)tid * 256;
        for (int k = 0; k < 256; k += 4) {
            float4 wv = *(const float4*)&wr[k];
            s = fmaf(h1[k], wv.x, s); s = fmaf(h1[k + 1], wv.y, s);
            s = fmaf(h1[k + 2], wv.z, s); s = fmaf(h1[k + 3], wv.w, s);
        }
        h2a[tid] = fmaxf(s, 0.0f);
    }
    __syncthreads();
    // cat path layer 1 (600->256), reuses h1
    {
        float s = ccf_b1[tid];
        const float* wr = ccf_w1 + (size_t)tid * 600;
        for (int k = 0; k < 600; k += 4) {
            float4 wv = *(const float4*)&wr[k];
            s = fmaf(vv[k], wv.x, s); s = fmaf(vv[k + 1], wv.y, s);
            s = fmaf(vv[k + 2], wv.z, s); s = fmaf(vv[k + 3], wv.w, s);
        }
        h1[tid] = fmaxf(s, 0.0f);
    }
    __syncthreads();
    if (tid < 128) {
        float s = ccf_b2[tid];
        const float* wr = ccf_w2 + (size_t)tid * 256;
        for (int k = 0; k < 256; k += 4) {
            float4 wv = *(const float4*)&wr[k];
            s = fmaf(h1[k], wv.x, s); s = fmaf(h1[k + 1], wv.y, s);
            s = fmaf(h1[k + 2], wv.z, s); s = fmaf(h1[k + 3], wv.w, s);
        }
        h2b[tid] = fmaxf(s, 0.0f);
    }
    __syncthreads();
    if (tid < 2) {
        float s = bout[tid];
        const float* wr = Wout + (size_t)tid * 256;
        for (int k = 0; k < 128; ++k) {
            s = fmaf(h2a[k], wr[k], s);
            s = fmaf(h2b[k], wr[128 + k], s);
        }
        out[(size_t)b * 2 + tid] = s;
    }
}

extern "C" void kernel_launch(void* const* d_in, const int* in_sizes, int n_in,
                              void* d_out, int out_size, void* d_ws, size_t ws_size,
                              hipStream_t stream) {
    const float* feat1  = (const float*)d_in[0];
    const float* feat2  = (const float*)d_in[1];
    const float* feat3  = (const float*)d_in[2];
    const float* Wa     = (const float*)d_in[3];
    const float* ba     = (const float*)d_in[4];
    const float* Wb     = (const float*)d_in[5];
    const float* bb     = (const float*)d_in[6];
    const float* Wc     = (const float*)d_in[7];
    const float* bc     = (const float*)d_in[8];
    const float* Wcorr  = (const float*)d_in[9];
    const float* bcorr  = (const float*)d_in[10];
    const float* Wcat   = (const float*)d_in[11];
    const float* bcat   = (const float*)d_in[12];
    const float* cf_w1  = (const float*)d_in[13];
    const float* cf_b1  = (const float*)d_in[14];
    const float* cf_w2  = (const float*)d_in[15];
    const float* cf_b2  = (const float*)d_in[16];
    const float* ccf_w1 = (const float*)d_in[17];
    const float* ccf_b1 = (const float*)d_in[18];
    const float* ccf_w2 = (const float*)d_in[19];
    const float* ccf_b2 = (const float*)d_in[20];
    const float* Wout   = (const float*)d_in[21];
    const float* bout   = (const float*)d_in[22];

    char* ws = (char*)d_ws;
    u16*  fbuf  = (u16*)(ws + OFF_F);
    u16*  corr  = (u16*)(ws + OFF_CORR);
    float* wct   = (float*)(ws + OFF_WCT);
    float* wcatt = (float*)(ws + OFF_WCATT);
    float* cflat = (float*)(ws + OFF_CFLAT);
    float* vflat = (float*)(ws + OFF_VFLAT);

    hipMemsetAsync(ws + OFF_CORR, 0, SZ_CORR, stream);
    k_prep<<<303, 256, 0, stream>>>(Wcorr, Wcat, wct, wcatt);
    k_conv1x1<<<dim3(8, 384, 4), 256, 0, stream>>>(feat1, feat2, feat3,
                                                   Wa, ba, Wb, bb, Wc, bc, fbuf);
    k_gram<<<dim3(16, 384), 256, 0, stream>>>(fbuf, corr);
    k_corrconv<<<dim3(10, 128), 256, 0, stream>>>(corr, wct, bcorr, cflat);
    k_catconv<<<dim3(10, 128), 256, 0, stream>>>(fbuf, wcatt, bcat, vflat);
    k_mlp<<<128, 256, 0, stream>>>(cflat, vflat, cf_w1, cf_b1, cf_w2, cf_b2,
                                   ccf_w1, ccf_b1, ccf_w2, ccf_b2, Wout, bout,
                                   (float*)d_out);
}

// Round 2
// 1324.203 us; speedup vs baseline: 1.5335x; 1.5335x over previous
//
#include <hip/hip_runtime.h>
#include <stdint.h>

#define NB 128
#define NC 512
#define NH 10
#define NW 20
#define NP 200      // NH*NW
#define ND3 1323
#define ND3P 1328   // padded channel count (16B-aligned rows)
#define MROWS 25600 // NB*NP flattened GEMM rows per tensor

typedef unsigned short u16;
typedef unsigned int u32;

typedef short bh8 __attribute__((ext_vector_type(8)));   // 8 bf16 (4 VGPRs)
typedef float f4 __attribute__((ext_vector_type(4)));    // 4 fp32 acc

// ---- workspace layout (bytes) ----
// fa (bf16 transposed feats) and corr (bf16 cost volume) ALIAS: fa is dead
// before corr is first written (memset placed after k_conv1x1_mfma).
#define OFF_FA     0ULL
#define SZ_FA      (3ULL*MROWS*NC*2)          // 78,643,200
#define OFF_CORR   0ULL
#define SZ_CORR    (1ULL*NB*NP*ND3P*2)        // 67,993,600 (<= SZ_FA)
#define OFF_FT     (OFF_FA + SZ_FA)
#define SZ_FT      (3ULL*MROWS*NC*2 + 65536)  // +64 pad rows for gram over-read
#define OFF_WBF    (OFF_FT + SZ_FT)
#define SZ_WBF     (3ULL*NC*NC*2)
#define OFF_WCT    (OFF_WBF + SZ_WBF)
#define SZ_WCT     (9ULL*3*ND3P*4)
#define OFF_WCATT  (OFF_WCT + SZ_WCT)
#define SZ_WCATT   (9ULL*3*1536*4)
#define OFF_CFLAT  (OFF_WCATT + SZ_WCATT)
#define SZ_CFLAT   (1ULL*NB*600*4)
#define OFF_VFLAT  (OFF_CFLAT + SZ_CFLAT)
#define SZ_VFLAT   (1ULL*NB*600*4)

__device__ __forceinline__ float bf2f(u16 a) {
    return __uint_as_float(((u32)a) << 16);
}
__device__ __forceinline__ u16 f2bf(float x) {
    u32 u = __float_as_uint(x);
    return (u16)((u + 0x7fffu + ((u >> 16) & 1u)) >> 16);
}

// ---- prep: transpose 3x3-conv weights; convert 1x1 weights to bf16 ----
__global__ __launch_bounds__(256) void k_prep(const float* __restrict__ Wcorr,
                                              const float* __restrict__ Wcat,
                                              const float* __restrict__ Wa,
                                              const float* __restrict__ Wb,
                                              const float* __restrict__ Wc,
                                              float* __restrict__ wct,
                                              float* __restrict__ wcatt,
                                              u16* __restrict__ wbf) {
    int idx = blockIdx.x * 256 + threadIdx.x;
    const int n1 = 9 * 3 * ND3P;       // 35856
    const int n2 = 9 * 3 * 1536;       // 41472
    const int n3 = 3 * NC * NC;        // 786432
    if (idx < n1) {
        int d = idx % ND3P;
        int r = idx / ND3P;
        int o = r % 3, k9 = r / 3;
        int ky = k9 / 3, kx = k9 % 3;
        float v = 0.0f;
        if (d < ND3) v = Wcorr[((o * ND3 + d) * 3 + ky) * 3 + kx];
        wct[idx] = v;
    } else if (idx < n1 + n2) {
        int j = idx - n1;
        int i = j % 1536;
        int r = j / 1536;
        int o = r % 3, k9 = r / 3;
        int ky = k9 / 3, kx = k9 % 3;
        wcatt[j] = Wcat[((o * 1536 + i) * 3 + ky) * 3 + kx];
    } else if (idx < n1 + n2 + n3) {
        int j = idx - n1 - n2;
        int t = j >> 18;               // 512*512 = 2^18
        const float* W = (t == 0) ? Wa : (t == 1) ? Wb : Wc;
        wbf[j] = f2bf(W[j & 262143]);
    }
}

// ---- transpose feat [t][b][c][p] f32 -> fa [t][(b,p)][c] bf16 ----
// grid (8 ctiles, 3*128), block 256
__global__ __launch_bounds__(256) void k_fa(const float* __restrict__ feat1,
                                            const float* __restrict__ feat2,
                                            const float* __restrict__ feat3,
                                            u16* __restrict__ fa) {
    const int tid = threadIdx.x;
    const int ct = blockIdx.x;
    const int t = blockIdx.y >> 7, b = blockIdx.y & 127;
    const float* feat = (t == 0) ? feat1 : (t == 1) ? feat2 : feat3;

    __shared__ u16 Ls[NP * 72];   // [p][c_local], padded stride

    const int cl = tid >> 2;          // 0..63
    const int pc = tid & 3;           // p chunk of 50
    const float* src = feat + ((size_t)b * NC + ct * 64 + cl) * NP + pc * 50;
#pragma unroll
    for (int u = 0; u < 50; u += 2) {
        float2 v = *(const float2*)(src + u);
        int p = pc * 50 + u;
        Ls[p * 72 + cl] = f2bf(v.x);
        Ls[(p + 1) * 72 + cl] = f2bf(v.y);
    }
    __syncthreads();
    for (int idx = tid; idx < 1600; idx += 256) {
        int p = idx >> 3, ck = idx & 7;
        uint4 v = *(const uint4*)&Ls[p * 72 + ck * 8];
        *(uint4*)&fa[((size_t)t * MROWS + b * NP + p) * NC + ct * 64 + ck * 8] = v;
    }
}

// ---- 1x1 conv as MFMA GEMM: fT[t][m][o] = fa[t][m][:] . W[t][o][:] + b ----
// grid (200 mtiles, 4 ntiles, 3), block 256 = 4 waves, tile 128x128, BK=64
#define LDA 72
__global__ __launch_bounds__(256) void k_conv1x1_mfma(
    const u16* __restrict__ fa, const u16* __restrict__ wbf,
    const float* __restrict__ ba, const float* __restrict__ bb,
    const float* __restrict__ bc, u16* __restrict__ fT) {
    const int tid = threadIdx.x;
    const int mb = blockIdx.x;
    const int nb = blockIdx.y;
    const int t = blockIdx.z;
    const float* bias = (t == 0) ? ba : (t == 1) ? bb : bc;

    __shared__ u16 As[128 * LDA];
    __shared__ u16 Bs[128 * LDA];

    const u16* Ag = fa + (size_t)t * MROWS * NC + (size_t)mb * 128 * NC;
    const u16* Bg = wbf + (size_t)t * NC * NC + (size_t)nb * 128 * NC;

    const int lane = tid & 63;
    const int wave = tid >> 6;
    const int wm = (wave & 1) * 64;
    const int wn = (wave >> 1) * 64;
    const int quad = lane >> 4;
    const int ln16 = lane & 15;

    f4 acc[4][4];
    const f4 zz = {0.f, 0.f, 0.f, 0.f};
#pragma unroll
    for (int i = 0; i < 4; ++i)
#pragma unroll
        for (int j = 0; j < 4; ++j) acc[i][j] = zz;

    uint4 ga[4], gb[4];
#pragma unroll
    for (int i = 0; i < 4; ++i) {
        int idx = tid + 256 * i;
        int r = idx >> 3, ck = idx & 7;
        ga[i] = *(const uint4*)(Ag + (size_t)r * NC + ck * 8);
        gb[i] = *(const uint4*)(Bg + (size_t)r * NC + ck * 8);
    }
    for (int ks = 0; ks < 8; ++ks) {
        __syncthreads();
#pragma unroll
        for (int i = 0; i < 4; ++i) {
            int idx = tid + 256 * i;
            int r = idx >> 3, ck = idx & 7;
            *(uint4*)&As[r * LDA + ck * 8] = ga[i];
            *(uint4*)&Bs[r * LDA + ck * 8] = gb[i];
        }
        __syncthreads();
        if (ks < 7) {
            int kof = (ks + 1) * 64;
#pragma unroll
            for (int i = 0; i < 4; ++i) {
                int idx = tid + 256 * i;
                int r = idx >> 3, ck = idx & 7;
                ga[i] = *(const uint4*)(Ag + (size_t)r * NC + kof + ck * 8);
                gb[i] = *(const uint4*)(Bg + (size_t)r * NC + kof + ck * 8);
            }
        }
#pragma unroll
        for (int h = 0; h < 2; ++h) {
            bh8 afr[4], bfr[4];
#pragma unroll
            for (int s = 0; s < 4; ++s) {
                afr[s] = *(const bh8*)&As[(wm + s * 16 + ln16) * LDA + h * 32 + quad * 8];
                bfr[s] = *(const bh8*)&Bs[(wn + s * 16 + ln16) * LDA + h * 32 + quad * 8];
            }
#pragma unroll
            for (int i = 0; i < 4; ++i)
#pragma unroll
                for (int j = 0; j < 4; ++j)
                    acc[i][j] = __builtin_amdgcn_mfma_f32_16x16x32_bf16(
                        afr[i], bfr[j], acc[i][j], 0, 0, 0);
        }
    }
    const int row0 = mb * 128 + wm + quad * 4;
    const int col0 = nb * 128 + wn + ln16;
#pragma unroll
    for (int j = 0; j < 4; ++j) {
        int n = col0 + j * 16;
        float bi = bias[n];
#pragma unroll
        for (int i = 0; i < 4; ++i) {
            int m0 = row0 + i * 16;
#pragma unroll
            for (int r = 0; r < 4; ++r) {
                float v = acc[i][j][r] + bi;
                fT[((size_t)t * MROWS + m0 + r) * NC + n] = f2bf(v);
            }
        }
    }
}

// ---- Gram via MFMA + /512 + leaky_relu + parity scatter into corr ----
// grid (2 mtiles, 2 ntiles, 3*128), block 256
__global__ __launch_bounds__(256) void k_gram_mfma(const u16* __restrict__ fT,
                                                   u16* __restrict__ corr) {
    const int tid = threadIdx.x;
    const int mt = blockIdx.x, nt = blockIdx.y;
    const int pair = blockIdx.z >> 7, b = blockIdx.z & 127;
    const int tA = (pair == 2) ? 1 : 0;
    const int tB = (pair == 0) ? 1 : 2;

    __shared__ u16 As[128 * LDA];
    __shared__ u16 Bs[128 * LDA];

    const u16* Ag = fT + ((size_t)tA * NB + b) * NP * NC + (size_t)mt * 128 * NC;
    const u16* Bg = fT + ((size_t)tB * NB + b) * NP * NC + (size_t)nt * 128 * NC;

    const int lane = tid & 63;
    const int wave = tid >> 6;
    const int wm = (wave & 1) * 64;
    const int wn = (wave >> 1) * 64;
    const int quad = lane >> 4;
    const int ln16 = lane & 15;

    f4 acc[4][4];
    const f4 zz = {0.f, 0.f, 0.f, 0.f};
#pragma unroll
    for (int i = 0; i < 4; ++i)
#pragma unroll
        for (int j = 0; j < 4; ++j) acc[i][j] = zz;

    uint4 ga[4], gb[4];
#pragma unroll
    for (int i = 0; i < 4; ++i) {
        int idx = tid + 256 * i;
        int r = idx >> 3, ck = idx & 7;
        ga[i] = *(const uint4*)(Ag + (size_t)r * NC + ck * 8);
        gb[i] = *(const uint4*)(Bg + (size_t)r * NC + ck * 8);
    }
    for (int ks = 0; ks < 8; ++ks) {
        __syncthreads();
#pragma unroll
        for (int i = 0; i < 4; ++i) {
            int idx = tid + 256 * i;
            int r = idx >> 3, ck = idx & 7;
            *(uint4*)&As[r * LDA + ck * 8] = ga[i];
            *(uint4*)&Bs[r * LDA + ck * 8] = gb[i];
        }
        __syncthreads();
        if (ks < 7) {
            int kof = (ks + 1) * 64;
#pragma unroll
            for (int i = 0; i < 4; ++i) {
                int idx = tid + 256 * i;
                int r = idx >> 3, ck = idx & 7;
                ga[i] = *(const uint4*)(Ag + (size_t)r * NC + kof + ck * 8);
                gb[i] = *(const uint4*)(Bg + (size_t)r * NC + kof + ck * 8);
            }
        }
#pragma unroll
        for (int h = 0; h < 2; ++h) {
            bh8 afr[4], bfr[4];
#pragma unroll
            for (int s = 0; s < 4; ++s) {
                afr[s] = *(const bh8*)&As[(wm + s * 16 + ln16) * LDA + h * 32 + quad * 8];
                bfr[s] = *(const bh8*)&Bs[(wn + s * 16 + ln16) * LDA + h * 32 + quad * 8];
            }
#pragma unroll
            for (int i = 0; i < 4; ++i)
#pragma unroll
                for (int j = 0; j < 4; ++j)
                    acc[i][j] = __builtin_amdgcn_mfma_f32_16x16x32_bf16(
                        afr[i], bfr[j], acc[i][j], 0, 0, 0);
        }
    }
    const int row0 = mt * 128 + wm + quad * 4;
    const int col0 = nt * 128 + wn + ln16;
#pragma unroll
    for (int i = 0; i < 4; ++i) {
#pragma unroll
        for (int r = 0; r < 4; ++r) {
            int p1 = row0 + i * 16 + r;
            if (p1 >= NP) continue;
            int y1 = p1 / 20, x1 = p1 - y1 * 20;
#pragma unroll
            for (int j = 0; j < 4; ++j) {
                int p2 = col0 + j * 16;
                if (p2 >= NP) continue;
                int y2 = p2 / 20, x2 = p2 - y2 * 20;
                int oy = y2 - y1, ox = x2 - x1;
                if (((oy | ox) & 1) == 0) {
                    int ch = ((oy + 20) >> 1) * 21 + ((ox + 20) >> 1);
                    float v = acc[i][j][r] * (1.0f / 512.0f);
                    v = (v > 0.0f) ? v : 0.1f * v;
                    corr[((size_t)b * NP + p1) * ND3P + pair * 441 + ch] = f2bf(v);
                }
            }
        }
    }
}

// ---- 3x3 conv over corr (1323->3) + bias + relu -> cflat[b][600] ----
__global__ __launch_bounds__(256) void k_corrconv(const u16* __restrict__ corr,
                                                  const float* __restrict__ wct,
                                                  const float* __restrict__ bcorr,
                                                  float* __restrict__ cflat) {
    const int tid = threadIdx.x;
    const int y0 = blockIdx.x;
    const int b = blockIdx.y;
    float acc = 0.0f;
    if (tid < 240) {
        const int x = tid % 20;
        const int o = (tid / 20) % 3;
        const int dc = tid / 60;            // 0..3, chunks of 332
        for (int ky = 0; ky < 3; ++ky) {
            int yy = y0 + ky - 1;
            if (yy < 0 || yy >= NH) continue;
            for (int kx = 0; kx < 3; ++kx) {
                int xx = x + kx - 1;
                if (xx < 0 || xx >= NW) continue;
                int p = yy * 20 + xx;
                const ushort4* cp =
                    (const ushort4*)(corr + ((size_t)b * NP + p) * ND3P + dc * 332);
                const float4* wp =
                    (const float4*)(wct + ((size_t)(ky * 3 + kx) * 3 + o) * ND3P + dc * 332);
#pragma unroll 4
                for (int it = 0; it < 83; ++it) {
                    ushort4 cu = cp[it];
                    float4 wv = wp[it];
                    acc = fmaf(bf2f(cu.x), wv.x, acc);
                    acc = fmaf(bf2f(cu.y), wv.y, acc);
                    acc = fmaf(bf2f(cu.z), wv.z, acc);
                    acc = fmaf(bf2f(cu.w), wv.w, acc);
                }
            }
        }
    }
    __shared__ float red[256];
    red[tid] = acc;
    __syncthreads();
    if (tid < 60) {
        float s = red[tid] + red[tid + 60] + red[tid + 120] + red[tid + 180];
        int x = tid % 20, o = tid / 20;
        s += bcorr[o];
        s = fmaxf(s, 0.0f);
        cflat[(size_t)b * 600 + o * 200 + y0 * 20 + x] = s;
    }
}

// ---- 3x3 conv over concat(f1,f2,f3) (1536->3), fT layout [t][(b,p)][c] ----
__global__ __launch_bounds__(256) void k_catconv(const u16* __restrict__ fT,
                                                 const float* __restrict__ wcatt,
                                                 const float* __restrict__ bcat,
                                                 float* __restrict__ vflat) {
    const int tid = threadIdx.x;
    const int y0 = blockIdx.x;
    const int b = blockIdx.y;
    float acc = 0.0f;
    if (tid < 240) {
        const int x = tid % 20;
        const int o = (tid / 20) % 3;
        const int ic = tid / 60;          // chunks of 384 over i in [0,1536)
        const int base_i = ic * 384;
        for (int ky = 0; ky < 3; ++ky) {
            int yy = y0 + ky - 1;
            if (yy < 0 || yy >= NH) continue;
            for (int kx = 0; kx < 3; ++kx) {
                int xx = x + kx - 1;
                if (xx < 0 || xx >= NW) continue;
                int p = yy * 20 + xx;
                const float* wp = wcatt + ((size_t)(ky * 3 + kx) * 3 + o) * 1536 + base_i;
                int i = base_i, rem = 384, wi = 0;
                while (rem > 0) {
                    int t = i >> 9, c = i & 511;
                    int n = (rem < (512 - c)) ? rem : (512 - c);
                    const u16* fp = fT + (((size_t)t * NB + b) * NP + p) * NC + c;
                    for (int u = 0; u < n; u += 8) {
                        uint4 raw = *(const uint4*)(fp + u);
                        float4 w0 = *(const float4*)(wp + wi + u);
                        float4 w1 = *(const float4*)(wp + wi + u + 4);
                        acc = fmaf(__uint_as_float(raw.x << 16), w0.x, acc);
                        acc = fmaf(__uint_as_float(raw.x & 0xffff0000u), w0.y, acc);
                        acc = fmaf(__uint_as_float(raw.y << 16), w0.z, acc);
                        acc = fmaf(__uint_as_float(raw.y & 0xffff0000u), w0.w, acc);
                        acc = fmaf(__uint_as_float(raw.z << 16), w1.x, acc);
                        acc = fmaf(__uint_as_float(raw.z & 0xffff0000u), w1.y, acc);
                        acc = fmaf(__uint_as_float(raw.w << 16), w1.z, acc);
                        acc = fmaf(__uint_as_float(raw.w & 0xffff0000u), w1.w, acc);
                    }
                    i += n; wi += n; rem -= n;
                }
            }
        }
    }
    __shared__ float red[256];
    red[tid] = acc;
    __syncthreads();
    if (tid < 60) {
        float s = red[tid] + red[tid + 60] + red[tid + 120] + red[tid + 180];
        int x = tid % 20, o = tid / 20;
        s += bcat[o];
        vflat[(size_t)b * 600 + o * 200 + y0 * 20 + x] = s;
    }
}

// ---- fused MLPs + final linear. grid 128 ----
__global__ __launch_bounds__(256) void k_mlp(
    const float* __restrict__ cflat, const float* __restrict__ vflat,
    const float* __restrict__ cf_w1, const float* __restrict__ cf_b1,
    const float* __restrict__ cf_w2, const float* __restrict__ cf_b2,
    const float* __restrict__ ccf_w1, const float* __restrict__ ccf_b1,
    const float* __restrict__ ccf_w2, const float* __restrict__ ccf_b2,
    const float* __restrict__ Wout, const float* __restrict__ bout,
    float* __restrict__ out) {
    const int tid = threadIdx.x;
    const int b = blockIdx.x;
    __shared__ float cv[600], vv[600], h1[256], h2a[128], h2b[128];
    for (int k = tid; k < 600; k += 256) {
        cv[k] = cflat[(size_t)b * 600 + k];
        vv[k] = vflat[(size_t)b * 600 + k];
    }
    __syncthreads();
    {
        float s = cf_b1[tid];
        const float* wr = cf_w1 + (size_t)tid * 600;
        for (int k = 0; k < 600; k += 4) {
            float4 wv = *(const float4*)&wr[k];
            s = fmaf(cv[k], wv.x, s); s = fmaf(cv[k + 1], wv.y, s);
            s = fmaf(cv[k + 2], wv.z, s); s = fmaf(cv[k + 3], wv.w, s);
        }
        h1[tid] = fmaxf(s, 0.0f);
    }
    __syncthreads();
    if (tid < 128) {
        float s = cf_b2[tid];
        const float* wr = cf_w2 + (size_t)tid * 256;
        for (int k = 0; k < 256; k += 4) {
            float4 wv = *(const float4*)&wr[k];
            s = fmaf(h1[k], wv.x, s); s = fmaf(h1[k + 1], wv.y, s);
            s = fmaf(h1[k + 2], wv.z, s); s = fmaf(h1[k + 3], wv.w, s);
        }
        h2a[tid] = fmaxf(s, 0.0f);
    }
    __syncthreads();
    {
        float s = ccf_b1[tid];
        const float* wr = ccf_w1 + (size_t)tid * 600;
        for (int k = 0; k < 600; k += 4) {
            float4 wv = *(const float4*)&wr[k];
            s = fmaf(vv[k], wv.x, s); s = fmaf(vv[k + 1], wv.y, s);
            s = fmaf(vv[k + 2], wv.z, s); s = fmaf(vv[k + 3], wv.w, s);
        }
        h1[tid] = fmaxf(s, 0.0f);
    }
    __syncthreads();
    if (tid < 128) {
        float s = ccf_b2[tid];
        const float* wr = ccf_w2 + (size_t)tid * 256;
        for (int k = 0; k < 256; k += 4) {
            float4 wv = *(const float4*)&wr[k];
            s = fmaf(h1[k], wv.x, s); s = fmaf(h1[k + 1], wv.y, s);
            s = fmaf(h1[k + 2], wv.z, s); s = fmaf(h1[k + 3], wv.w, s);
        }
        h2b[tid] = fmaxf(s, 0.0f);
    }
    __syncthreads();
    if (tid < 2) {
        float s = bout[tid];
        const float* wr = Wout + (size_t)tid * 256;
        for (int k = 0; k < 128; ++k) {
            s = fmaf(h2a[k], wr[k], s);
            s = fmaf(h2b[k], wr[128 + k], s);
        }
        out[(size_t)b * 2 + tid] = s;
    }
}

extern "C" void kernel_launch(void* const* d_in, const int* in_sizes, int n_in,
                              void* d_out, int out_size, void* d_ws, size_t ws_size,
                              hipStream_t stream) {
    const float* feat1  = (const float*)d_in[0];
    const float* feat2  = (const float*)d_in[1];
    const float* feat3  = (const float*)d_in[2];
    const float* Wa     = (const float*)d_in[3];
    const float* ba     = (const float*)d_in[4];
    const float* Wb     = (const float*)d_in[5];
    const float* bb     = (const float*)d_in[6];
    const float* Wc     = (const float*)d_in[7];
    const float* bc     = (const float*)d_in[8];
    const float* Wcorr  = (const float*)d_in[9];
    const float* bcorr  = (const float*)d_in[10];
    const float* Wcat   = (const float*)d_in[11];
    const float* bcat   = (const float*)d_in[12];
    const float* cf_w1  = (const float*)d_in[13];
    const float* cf_b1  = (const float*)d_in[14];
    const float* cf_w2  = (const float*)d_in[15];
    const float* cf_b2  = (const float*)d_in[16];
    const float* ccf_w1 = (const float*)d_in[17];
    const float* ccf_b1 = (const float*)d_in[18];
    const float* ccf_w2 = (const float*)d_in[19];
    const float* ccf_b2 = (const float*)d_in[20];
    const float* Wout   = (const float*)d_in[21];
    const float* bout   = (const float*)d_in[22];

    char* ws = (char*)d_ws;
    u16*  fa    = (u16*)(ws + OFF_FA);
    u16*  corr  = (u16*)(ws + OFF_CORR);   // aliases fa (disjoint lifetimes)
    u16*  fT    = (u16*)(ws + OFF_FT);
    u16*  wbf   = (u16*)(ws + OFF_WBF);
    float* wct   = (float*)(ws + OFF_WCT);
    float* wcatt = (float*)(ws + OFF_WCATT);
    float* cflat = (float*)(ws + OFF_CFLAT);
    float* vflat = (float*)(ws + OFF_VFLAT);

    k_prep<<<3375, 256, 0, stream>>>(Wcorr, Wcat, Wa, Wb, Wc, wct, wcatt, wbf);
    k_fa<<<dim3(8, 384), 256, 0, stream>>>(feat1, feat2, feat3, fa);
    k_conv1x1_mfma<<<dim3(200, 4, 3), 256, 0, stream>>>(fa, wbf, ba, bb, bc, fT);
    hipMemsetAsync(ws + OFF_CORR, 0, SZ_CORR, stream);   // fa dead from here
    k_gram_mfma<<<dim3(2, 2, 384), 256, 0, stream>>>(fT, corr);
    k_corrconv<<<dim3(10, 128), 256, 0, stream>>>(corr, wct, bcorr, cflat);
    k_catconv<<<dim3(10, 128), 256, 0, stream>>>(fT, wcatt, bcat, vflat);
    k_mlp<<<128, 256, 0, stream>>>(cflat, vflat, cf_w1, cf_b1, cf_w2, cf_b2,
                                   ccf_w1, ccf_b1, ccf_w2, ccf_b2, Wout, bout,
                                   (float*)d_out);
}

// Round 3
// 747.528 us; speedup vs baseline: 2.7166x; 1.7714x over previous
//
#include <hip/hip_runtime.h>
#include <stdint.h>

#define NB 128
#define NC 512
#define NH 10
#define NW 20
#define NP 200      // NH*NW
#define ND3 1323
#define ND3P 1328   // padded channel count (16B-aligned rows)
#define MROWS 25600 // NB*NP flattened GEMM rows per tensor
#define KCORR 1344  // 21*64 K-loop extent for corr conv-GEMM
#define KCAT  1536  // 24*64

typedef unsigned short u16;
typedef unsigned int u32;

typedef short bh8 __attribute__((ext_vector_type(8)));   // 8 bf16 (4 VGPRs)
typedef float f4 __attribute__((ext_vector_type(4)));    // 4 fp32 acc

// ---- workspace layout (bytes) ----
// fa (bf16 transposed feats) occupies [0, 78.6MB). After k_conv1x1_mfma it is
// dead; corr (68MB) + 64B zero pad + Ucorr/Ucat alias into that region.
#define OFF_FA     0ULL
#define SZ_FA      (3ULL*MROWS*NC*2)             // 78,643,200
#define OFF_CORR   0ULL
#define SZ_CORR    (1ULL*NB*NP*ND3P*2)           // 67,993,600
#define OFF_UCORR  (OFF_CORR + SZ_CORR + 256)    // inside old fa region
#define SZ_U       (1ULL*MROWS*32*4)             // 3,276,800
#define OFF_UCAT   (OFF_UCORR + SZ_U)            // ends at ~74.5MB < 78.6MB
#define OFF_FT     (OFF_FA + SZ_FA)
#define SZ_FT      (3ULL*MROWS*NC*2 + 65536)     // +pad rows for gram over-read
#define OFF_WBF    (OFF_FT + SZ_FT)
#define SZ_WBF     (3ULL*NC*NC*2)
#define OFF_WCTB   (OFF_WBF + SZ_WBF)
#define SZ_WCTB    (32ULL*KCORR*2)               // bf16 [32][1344]
#define OFF_WCATB  (OFF_WCTB + SZ_WCTB)
#define SZ_WCATB   (32ULL*KCAT*2)                // bf16 [32][1536]
#define OFF_CFLAT  (OFF_WCATB + SZ_WCATB)
#define SZ_CFLAT   (1ULL*NB*600*4)
#define OFF_VFLAT  (OFF_CFLAT + SZ_CFLAT)
#define SZ_VFLAT   (1ULL*NB*600*4)

__device__ __forceinline__ float bf2f(u16 a) {
    return __uint_as_float(((u32)a) << 16);
}
__device__ __forceinline__ u16 f2bf(float x) {
    u32 u = __float_as_uint(x);
    return (u16)((u + 0x7fffu + ((u >> 16) & 1u)) >> 16);
}

// ---- prep: build bf16 weight matrices ----
// wctb [n=tap*3+o][d]  (32 x 1344, zeros beyond n=27 / d=1323)
// wcatb[n=tap*3+o][i]  (32 x 1536, zeros beyond n=27)
// wbf  [t][o][c] bf16 of 1x1 weights
__global__ __launch_bounds__(256) void k_prep(const float* __restrict__ Wcorr,
                                              const float* __restrict__ Wcat,
                                              const float* __restrict__ Wa,
                                              const float* __restrict__ Wb,
                                              const float* __restrict__ Wc,
                                              u16* __restrict__ wctb,
                                              u16* __restrict__ wcatb,
                                              u16* __restrict__ wbf) {
    int idx = blockIdx.x * 256 + threadIdx.x;
    const int n1 = 32 * KCORR;     // 43008
    const int n2 = 32 * KCAT;      // 49152
    const int n3 = 3 * NC * NC;    // 786432
    if (idx < n1) {
        int d = idx % KCORR;
        int n = idx / KCORR;
        float v = 0.0f;
        if (n < 27 && d < ND3) {
            int tap = n / 3, o = n % 3;
            int ky = tap / 3, kx = tap % 3;
            v = Wcorr[((o * ND3 + d) * 3 + ky) * 3 + kx];
        }
        wctb[idx] = f2bf(v);
    } else if (idx < n1 + n2) {
        int j = idx - n1;
        int i = j % KCAT;
        int n = j / KCAT;
        float v = 0.0f;
        if (n < 27) {
            int tap = n / 3, o = n % 3;
            int ky = tap / 3, kx = tap % 3;
            v = Wcat[((o * 1536 + i) * 3 + ky) * 3 + kx];
        }
        wcatb[j] = f2bf(v);
    } else if (idx < n1 + n2 + n3) {
        int j = idx - n1 - n2;
        int t = j >> 18;
        const float* W = (t == 0) ? Wa : (t == 1) ? Wb : Wc;
        wbf[j] = f2bf(W[j & 262143]);
    }
}

// ---- transpose feat [t][b][c][p] f32 -> fa [t][(b,p)][c] bf16 ----
__global__ __launch_bounds__(256) void k_fa(const float* __restrict__ feat1,
                                            const float* __restrict__ feat2,
                                            const float* __restrict__ feat3,
                                            u16* __restrict__ fa) {
    const int tid = threadIdx.x;
    const int ct = blockIdx.x;
    const int t = blockIdx.y >> 7, b = blockIdx.y & 127;
    const float* feat = (t == 0) ? feat1 : (t == 1) ? feat2 : feat3;

    __shared__ u16 Ls[NP * 72];

    const int cl = tid >> 2;
    const int pc = tid & 3;
    const float* src = feat + ((size_t)b * NC + ct * 64 + cl) * NP + pc * 50;
#pragma unroll
    for (int u = 0; u < 50; u += 2) {
        float2 v = *(const float2*)(src + u);
        int p = pc * 50 + u;
        Ls[p * 72 + cl] = f2bf(v.x);
        Ls[(p + 1) * 72 + cl] = f2bf(v.y);
    }
    __syncthreads();
    for (int idx = tid; idx < 1600; idx += 256) {
        int p = idx >> 3, ck = idx & 7;
        uint4 v = *(const uint4*)&Ls[p * 72 + ck * 8];
        *(uint4*)&fa[((size_t)t * MROWS + b * NP + p) * NC + ct * 64 + ck * 8] = v;
    }
}

// ---- 1x1 conv as MFMA GEMM ----
#define LDA 72
__global__ __launch_bounds__(256) void k_conv1x1_mfma(
    const u16* __restrict__ fa, const u16* __restrict__ wbf,
    const float* __restrict__ ba, const float* __restrict__ bb,
    const float* __restrict__ bc, u16* __restrict__ fT) {
    const int tid = threadIdx.x;
    const int mb = blockIdx.x;
    const int nb = blockIdx.y;
    const int t = blockIdx.z;
    const float* bias = (t == 0) ? ba : (t == 1) ? bb : bc;

    __shared__ u16 As[128 * LDA];
    __shared__ u16 Bs[128 * LDA];

    const u16* Ag = fa + (size_t)t * MROWS * NC + (size_t)mb * 128 * NC;
    const u16* Bg = wbf + (size_t)t * NC * NC + (size_t)nb * 128 * NC;

    const int lane = tid & 63;
    const int wave = tid >> 6;
    const int wm = (wave & 1) * 64;
    const int wn = (wave >> 1) * 64;
    const int quad = lane >> 4;
    const int ln16 = lane & 15;

    f4 acc[4][4];
    const f4 zz = {0.f, 0.f, 0.f, 0.f};
#pragma unroll
    for (int i = 0; i < 4; ++i)
#pragma unroll
        for (int j = 0; j < 4; ++j) acc[i][j] = zz;

    uint4 ga[4], gb[4];
#pragma unroll
    for (int i = 0; i < 4; ++i) {
        int idx = tid + 256 * i;
        int r = idx >> 3, ck = idx & 7;
        ga[i] = *(const uint4*)(Ag + (size_t)r * NC + ck * 8);
        gb[i] = *(const uint4*)(Bg + (size_t)r * NC + ck * 8);
    }
    for (int ks = 0; ks < 8; ++ks) {
        __syncthreads();
#pragma unroll
        for (int i = 0; i < 4; ++i) {
            int idx = tid + 256 * i;
            int r = idx >> 3, ck = idx & 7;
            *(uint4*)&As[r * LDA + ck * 8] = ga[i];
            *(uint4*)&Bs[r * LDA + ck * 8] = gb[i];
        }
        __syncthreads();
        if (ks < 7) {
            int kof = (ks + 1) * 64;
#pragma unroll
            for (int i = 0; i < 4; ++i) {
                int idx = tid + 256 * i;
                int r = idx >> 3, ck = idx & 7;
                ga[i] = *(const uint4*)(Ag + (size_t)r * NC + kof + ck * 8);
                gb[i] = *(const uint4*)(Bg + (size_t)r * NC + kof + ck * 8);
            }
        }
#pragma unroll
        for (int h = 0; h < 2; ++h) {
            bh8 afr[4], bfr[4];
#pragma unroll
            for (int s = 0; s < 4; ++s) {
                afr[s] = *(const bh8*)&As[(wm + s * 16 + ln16) * LDA + h * 32 + quad * 8];
                bfr[s] = *(const bh8*)&Bs[(wn + s * 16 + ln16) * LDA + h * 32 + quad * 8];
            }
#pragma unroll
            for (int i = 0; i < 4; ++i)
#pragma unroll
                for (int j = 0; j < 4; ++j)
                    acc[i][j] = __builtin_amdgcn_mfma_f32_16x16x32_bf16(
                        afr[i], bfr[j], acc[i][j], 0, 0, 0);
        }
    }
    const int row0 = mb * 128 + wm + quad * 4;
    const int col0 = nb * 128 + wn + ln16;
#pragma unroll
    for (int j = 0; j < 4; ++j) {
        int n = col0 + j * 16;
        float bi = bias[n];
#pragma unroll
        for (int i = 0; i < 4; ++i) {
            int m0 = row0 + i * 16;
#pragma unroll
            for (int r = 0; r < 4; ++r) {
                float v = acc[i][j][r] + bi;
                fT[((size_t)t * MROWS + m0 + r) * NC + n] = f2bf(v);
            }
        }
    }
}

// ---- Gram via MFMA + /512 + leaky_relu + parity scatter into corr ----
__global__ __launch_bounds__(256) void k_gram_mfma(const u16* __restrict__ fT,
                                                   u16* __restrict__ corr) {
    const int tid = threadIdx.x;
    const int mt = blockIdx.x, nt = blockIdx.y;
    const int pair = blockIdx.z >> 7, b = blockIdx.z & 127;
    const int tA = (pair == 2) ? 1 : 0;
    const int tB = (pair == 0) ? 1 : 2;

    __shared__ u16 As[128 * LDA];
    __shared__ u16 Bs[128 * LDA];

    const u16* Ag = fT + ((size_t)tA * NB + b) * NP * NC + (size_t)mt * 128 * NC;
    const u16* Bg = fT + ((size_t)tB * NB + b) * NP * NC + (size_t)nt * 128 * NC;

    const int lane = tid & 63;
    const int wave = tid >> 6;
    const int wm = (wave & 1) * 64;
    const int wn = (wave >> 1) * 64;
    const int quad = lane >> 4;
    const int ln16 = lane & 15;

    f4 acc[4][4];
    const f4 zz = {0.f, 0.f, 0.f, 0.f};
#pragma unroll
    for (int i = 0; i < 4; ++i)
#pragma unroll
        for (int j = 0; j < 4; ++j) acc[i][j] = zz;

    uint4 ga[4], gb[4];
#pragma unroll
    for (int i = 0; i < 4; ++i) {
        int idx = tid + 256 * i;
        int r = idx >> 3, ck = idx & 7;
        ga[i] = *(const uint4*)(Ag + (size_t)r * NC + ck * 8);
        gb[i] = *(const uint4*)(Bg + (size_t)r * NC + ck * 8);
    }
    for (int ks = 0; ks < 8; ++ks) {
        __syncthreads();
#pragma unroll
        for (int i = 0; i < 4; ++i) {
            int idx = tid + 256 * i;
            int r = idx >> 3, ck = idx & 7;
            *(uint4*)&As[r * LDA + ck * 8] = ga[i];
            *(uint4*)&Bs[r * LDA + ck * 8] = gb[i];
        }
        __syncthreads();
        if (ks < 7) {
            int kof = (ks + 1) * 64;
#pragma unroll
            for (int i = 0; i < 4; ++i) {
                int idx = tid + 256 * i;
                int r = idx >> 3, ck = idx & 7;
                ga[i] = *(const uint4*)(Ag + (size_t)r * NC + kof + ck * 8);
                gb[i] = *(const uint4*)(Bg + (size_t)r * NC + kof + ck * 8);
            }
        }
#pragma unroll
        for (int h = 0; h < 2; ++h) {
            bh8 afr[4], bfr[4];
#pragma unroll
            for (int s = 0; s < 4; ++s) {
                afr[s] = *(const bh8*)&As[(wm + s * 16 + ln16) * LDA + h * 32 + quad * 8];
                bfr[s] = *(const bh8*)&Bs[(wn + s * 16 + ln16) * LDA + h * 32 + quad * 8];
            }
#pragma unroll
            for (int i = 0; i < 4; ++i)
#pragma unroll
                for (int j = 0; j < 4; ++j)
                    acc[i][j] = __builtin_amdgcn_mfma_f32_16x16x32_bf16(
                        afr[i], bfr[j], acc[i][j], 0, 0, 0);
        }
    }
    const int row0 = mt * 128 + wm + quad * 4;
    const int col0 = nt * 128 + wn + ln16;
#pragma unroll
    for (int i = 0; i < 4; ++i) {
#pragma unroll
        for (int r = 0; r < 4; ++r) {
            int p1 = row0 + i * 16 + r;
            if (p1 >= NP) continue;
            int y1 = p1 / 20, x1 = p1 - y1 * 20;
#pragma unroll
            for (int j = 0; j < 4; ++j) {
                int p2 = col0 + j * 16;
                if (p2 >= NP) continue;
                int y2 = p2 / 20, x2 = p2 - y2 * 20;
                int oy = y2 - y1, ox = x2 - x1;
                if (((oy | ox) & 1) == 0) {
                    int ch = ((oy + 20) >> 1) * 21 + ((ox + 20) >> 1);
                    float v = acc[i][j][r] * (1.0f / 512.0f);
                    v = (v > 0.0f) ? v : 0.1f * v;
                    corr[((size_t)b * NP + p1) * ND3P + pair * 441 + ch] = f2bf(v);
                }
            }
        }
    }
}

// ---- conv as GEMM: U[m][n] = A[m][:] . Bn[n][:], n = tap*3+o (27, pad 32) ----
// mode 0: A = corr, rows [m][1328], K-extent 1344 (B zero beyond 1323)
// mode 1: A = fT (3 stacked [25600][512] mats), K = t*512+c, extent 1536
// grid 200, block 256 (4 waves); tile M=128, N=32, BK=64
__global__ __launch_bounds__(256) void k_convgemm(const u16* __restrict__ A0,
                                                  const u16* __restrict__ Bn,
                                                  float* __restrict__ U,
                                                  int kiters, int mode) {
    const int tid = threadIdx.x;
    const int mb = blockIdx.x;
    const int Kpad = kiters * 64;

    __shared__ u16 As[128 * LDA];
    __shared__ u16 Bs[32 * LDA];

    const int lane = tid & 63;
    const int wave = tid >> 6;
    const int wm = wave * 32;
    const int quad = lane >> 4;
    const int ln16 = lane & 15;

    const int ar = (tid * 4) >> 3;        // base row pattern: idx = tid + 256*i
    f4 acc00 = {0,0,0,0}, acc01 = {0,0,0,0}, acc10 = {0,0,0,0}, acc11 = {0,0,0,0};

    uint4 ga[4], gb1;
    // A global address helper (computed inline to keep uint4 alignment)
#define APTR(r, kabs) ((mode == 0) \
    ? (A0 + (size_t)(mb * 128 + (r)) * ND3P + (kabs)) \
    : (A0 + (((size_t)((kabs) >> 9) * MROWS + mb * 128 + (r)) * NC) + ((kabs) & 511)))

#pragma unroll
    for (int i = 0; i < 4; ++i) {
        int idx = tid + 256 * i;
        int r = idx >> 3, ck = idx & 7;
        ga[i] = *(const uint4*)APTR(r, ck * 8);
    }
    {
        int r = tid >> 3, ck = tid & 7;
        gb1 = *(const uint4*)(Bn + (size_t)r * Kpad + ck * 8);
    }
    for (int ks = 0; ks < kiters; ++ks) {
        __syncthreads();
#pragma unroll
        for (int i = 0; i < 4; ++i) {
            int idx = tid + 256 * i;
            int r = idx >> 3, ck = idx & 7;
            *(uint4*)&As[r * LDA + ck * 8] = ga[i];
        }
        {
            int r = tid >> 3, ck = tid & 7;
            *(uint4*)&Bs[r * LDA + ck * 8] = gb1;
        }
        __syncthreads();
        if (ks < kiters - 1) {
            int kof = (ks + 1) * 64;
#pragma unroll
            for (int i = 0; i < 4; ++i) {
                int idx = tid + 256 * i;
                int r = idx >> 3, ck = idx & 7;
                ga[i] = *(const uint4*)APTR(r, kof + ck * 8);
            }
            int r = tid >> 3, ck = tid & 7;
            gb1 = *(const uint4*)(Bn + (size_t)r * Kpad + kof + ck * 8);
        }
#pragma unroll
        for (int h = 0; h < 2; ++h) {
            bh8 a0 = *(const bh8*)&As[(wm + ln16) * LDA + h * 32 + quad * 8];
            bh8 a1 = *(const bh8*)&As[(wm + 16 + ln16) * LDA + h * 32 + quad * 8];
            bh8 b0 = *(const bh8*)&Bs[(ln16) * LDA + h * 32 + quad * 8];
            bh8 b1 = *(const bh8*)&Bs[(16 + ln16) * LDA + h * 32 + quad * 8];
            acc00 = __builtin_amdgcn_mfma_f32_16x16x32_bf16(a0, b0, acc00, 0, 0, 0);
            acc01 = __builtin_amdgcn_mfma_f32_16x16x32_bf16(a0, b1, acc01, 0, 0, 0);
            acc10 = __builtin_amdgcn_mfma_f32_16x16x32_bf16(a1, b0, acc10, 0, 0, 0);
            acc11 = __builtin_amdgcn_mfma_f32_16x16x32_bf16(a1, b1, acc11, 0, 0, 0);
        }
    }
#undef APTR
    const int rbase = mb * 128 + wm + quad * 4;
#pragma unroll
    for (int r = 0; r < 4; ++r) {
        U[(size_t)(rbase + r) * 32 + ln16] = acc00[r];
        U[(size_t)(rbase + r) * 32 + 16 + ln16] = acc01[r];
        U[(size_t)(rbase + 16 + r) * 32 + ln16] = acc10[r];
        U[(size_t)(rbase + 16 + r) * 32 + 16 + ln16] = acc11[r];
    }
}

// ---- 9-neighbor gather + bias (+relu for corr path) -> cflat/vflat ----
__global__ __launch_bounds__(256) void k_fix(const float* __restrict__ Ucorr,
                                             const float* __restrict__ Ucat,
                                             const float* __restrict__ bcorr,
                                             const float* __restrict__ bcat,
                                             float* __restrict__ cflat,
                                             float* __restrict__ vflat) {
    const int tid = threadIdx.x;
    const int b = blockIdx.x;
    __shared__ float Lc[NP][28];
    __shared__ float La[NP][28];
    for (int idx = tid; idx < NP * 27; idx += 256) {
        int p = idx / 27, n = idx - p * 27;
        Lc[p][n] = Ucorr[(size_t)(b * NP + p) * 32 + n];
        La[p][n] = Ucat[(size_t)(b * NP + p) * 32 + n];
    }
    __syncthreads();
    for (int idx = tid; idx < 1200; idx += 256) {
        int path = idx / 600;
        int rem = idx - path * 600;
        int o = rem / 200, p = rem - o * 200;
        int y = p / 20, x = p - y * 20;
        float s = (path == 0) ? bcorr[o] : bcat[o];
        for (int ky = 0; ky < 3; ++ky) {
            int yy = y + ky - 1;
            if (yy < 0 || yy >= NH) continue;
            for (int kx = 0; kx < 3; ++kx) {
                int xx = x + kx - 1;
                if (xx < 0 || xx >= NW) continue;
                int n = (ky * 3 + kx) * 3 + o;
                s += (path == 0) ? Lc[yy * 20 + xx][n] : La[yy * 20 + xx][n];
            }
        }
        if (path == 0) {
            s = fmaxf(s, 0.0f);
            cflat[(size_t)b * 600 + rem] = s;
        } else {
            vflat[(size_t)b * 600 + rem] = s;
        }
    }
}

// ---- fused MLPs + final linear. grid 128 ----
__global__ __launch_bounds__(256) void k_mlp(
    const float* __restrict__ cflat, const float* __restrict__ vflat,
    const float* __restrict__ cf_w1, const float* __restrict__ cf_b1,
    const float* __restrict__ cf_w2, const float* __restrict__ cf_b2,
    const float* __restrict__ ccf_w1, const float* __restrict__ ccf_b1,
    const float* __restrict__ ccf_w2, const float* __restrict__ ccf_b2,
    const float* __restrict__ Wout, const float* __restrict__ bout,
    float* __restrict__ out) {
    const int tid = threadIdx.x;
    const int b = blockIdx.x;
    __shared__ float cv[600], vv[600], h1[256], h2a[128], h2b[128];
    for (int k = tid; k < 600; k += 256) {
        cv[k] = cflat[(size_t)b * 600 + k];
        vv[k] = vflat[(size_t)b * 600 + k];
    }
    __syncthreads();
    {
        float s = cf_b1[tid];
        const float* wr = cf_w1 + (size_t)tid * 600;
        for (int k = 0; k < 600; k += 4) {
            float4 wv = *(const float4*)&wr[k];
            s = fmaf(cv[k], wv.x, s); s = fmaf(cv[k + 1], wv.y, s);
            s = fmaf(cv[k + 2], wv.z, s); s = fmaf(cv[k + 3], wv.w, s);
        }
        h1[tid] = fmaxf(s, 0.0f);
    }
    __syncthreads();
    if (tid < 128) {
        float s = cf_b2[tid];
        const float* wr = cf_w2 + (size_t)tid * 256;
        for (int k = 0; k < 256; k += 4) {
            float4 wv = *(const float4*)&wr[k];
            s = fmaf(h1[k], wv.x, s); s = fmaf(h1[k + 1], wv.y, s);
            s = fmaf(h1[k + 2], wv.z, s); s = fmaf(h1[k + 3], wv.w, s);
        }
        h2a[tid] = fmaxf(s, 0.0f);
    }
    __syncthreads();
    {
        float s = ccf_b1[tid];
        const float* wr = ccf_w1 + (size_t)tid * 600;
        for (int k = 0; k < 600; k += 4) {
            float4 wv = *(const float4*)&wr[k];
            s = fmaf(vv[k], wv.x, s); s = fmaf(vv[k + 1], wv.y, s);
            s = fmaf(vv[k + 2], wv.z, s); s = fmaf(vv[k + 3], wv.w, s);
        }
        h1[tid] = fmaxf(s, 0.0f);
    }
    __syncthreads();
    if (tid < 128) {
        float s = ccf_b2[tid];
        const float* wr = ccf_w2 + (size_t)tid * 256;
        for (int k = 0; k < 256; k += 4) {
            float4 wv = *(const float4*)&wr[k];
            s = fmaf(h1[k], wv.x, s); s = fmaf(h1[k + 1], wv.y, s);
            s = fmaf(h1[k + 2], wv.z, s); s = fmaf(h1[k + 3], wv.w, s);
        }
        h2b[tid] = fmaxf(s, 0.0f);
    }
    __syncthreads();
    if (tid < 2) {
        float s = bout[tid];
        const float* wr = Wout + (size_t)tid * 256;
        for (int k = 0; k < 128; ++k) {
            s = fmaf(h2a[k], wr[k], s);
            s = fmaf(h2b[k], wr[128 + k], s);
        }
        out[(size_t)b * 2 + tid] = s;
    }
}

extern "C" void kernel_launch(void* const* d_in, const int* in_sizes, int n_in,
                              void* d_out, int out_size, void* d_ws, size_t ws_size,
                              hipStream_t stream) {
    const float* feat1  = (const float*)d_in[0];
    const float* feat2  = (const float*)d_in[1];
    const float* feat3  = (const float*)d_in[2];
    const float* Wa     = (const float*)d_in[3];
    const float* ba     = (const float*)d_in[4];
    const float* Wb     = (const float*)d_in[5];
    const float* bb     = (const float*)d_in[6];
    const float* Wc     = (const float*)d_in[7];
    const float* bc     = (const float*)d_in[8];
    const float* Wcorr  = (const float*)d_in[9];
    const float* bcorr  = (const float*)d_in[10];
    const float* Wcat   = (const float*)d_in[11];
    const float* bcat   = (const float*)d_in[12];
    const float* cf_w1  = (const float*)d_in[13];
    const float* cf_b1  = (const float*)d_in[14];
    const float* cf_w2  = (const float*)d_in[15];
    const float* cf_b2  = (const float*)d_in[16];
    const float* ccf_w1 = (const float*)d_in[17];
    const float* ccf_b1 = (const float*)d_in[18];
    const float* ccf_w2 = (const float*)d_in[19];
    const float* ccf_b2 = (const float*)d_in[20];
    const float* Wout   = (const float*)d_in[21];
    const float* bout   = (const float*)d_in[22];

    char* ws = (char*)d_ws;
    u16*  fa    = (u16*)(ws + OFF_FA);
    u16*  corr  = (u16*)(ws + OFF_CORR);   // aliases fa (disjoint lifetimes)
    float* Ucorr = (float*)(ws + OFF_UCORR); // aliases fa tail
    float* Ucat  = (float*)(ws + OFF_UCAT);
    u16*  fT    = (u16*)(ws + OFF_FT);
    u16*  wbf   = (u16*)(ws + OFF_WBF);
    u16*  wctb  = (u16*)(ws + OFF_WCTB);
    u16*  wcatb = (u16*)(ws + OFF_WCATB);
    float* cflat = (float*)(ws + OFF_CFLAT);
    float* vflat = (float*)(ws + OFF_VFLAT);

    k_prep<<<3432, 256, 0, stream>>>(Wcorr, Wcat, Wa, Wb, Wc, wctb, wcatb, wbf);
    k_fa<<<dim3(8, 384), 256, 0, stream>>>(feat1, feat2, feat3, fa);
    k_conv1x1_mfma<<<dim3(200, 4, 3), 256, 0, stream>>>(fa, wbf, ba, bb, bc, fT);
    // fa dead from here; zero corr + 64B pad (covers conv-GEMM tail over-read)
    hipMemsetAsync(ws + OFF_CORR, 0, SZ_CORR + 64, stream);
    k_gram_mfma<<<dim3(2, 2, 384), 256, 0, stream>>>(fT, corr);
    k_convgemm<<<200, 256, 0, stream>>>(corr, wctb, Ucorr, KCORR / 64, 0);
    k_convgemm<<<200, 256, 0, stream>>>(fT, wcatb, Ucat, KCAT / 64, 1);
    k_fix<<<128, 256, 0, stream>>>(Ucorr, Ucat, bcorr, bcat, cflat, vflat);
    k_mlp<<<128, 256, 0, stream>>>(cflat, vflat, cf_w1, cf_b1, cf_w2, cf_b2,
                                   ccf_w1, ccf_b1, ccf_w2, ccf_b2, Wout, bout,
                                   (float*)d_out);
}